// Round 4
// baseline (295.359 us; speedup 1.0000x reference)
//
#include <hip/hip_runtime.h>

#define TL 124
#define CL 144
#define HL 36

typedef unsigned short u16;
typedef short bf16x8 __attribute__((ext_vector_type(8)));
typedef float f32x4  __attribute__((ext_vector_type(4)));

// LDS (bytes), 40960 total -> 4 blocks/CU (4 x 40960 = 160 KiB exactly):
//   k   @ 0     : bf16 [124][40]  = 9920   (cols 36..39 written as zeros)
//   gap @ 9920  : 16 B zeros (phase-S zero fragment for K-tail, hi>=1)
//   q   @ 9936  : bf16 [124][40]  = 9920   (ends 19856)
//   wei @ 0     : bf16 [124][128] = 31744  (overlays k/gap/q after scores barrier; XOR-swizzled)
//   vT  @ 31744 : bf16 [36][128]  = 9216   (vT[h][t], XOR-swizzled)
#define KQ_ST   40
#define GAP_B   9920
#define Q_B     9936
#define VT_B    31744
#define ZEROP_B 128     // wei row 0, cols 64..71: guaranteed masked-zero after softmax
#define LDS_BYTES 40960

// ws image: bf16 [5 kchunks][144 h_padded][40 kcols]; h_padded = 48*sec + hh,
// sec 0/1/2 = Wk/Wq/Wv, hh<36 valid else 0; kcol = 32*chunk + kk, kk<32 & kc<144 valid.
#define WS_ELEMS (5 * 144 * 40)

__device__ __forceinline__ u16 f2b(float f) {
    union { float f; unsigned u; } c; c.f = f;
    unsigned u = c.u;
    u += 0x7FFFu + ((u >> 16) & 1u);     // round-to-nearest-even
    return (u16)(u >> 16);
}

__global__ void prepack_w(const float* __restrict__ Wk, const float* __restrict__ Wq,
                          const float* __restrict__ Wv, u16* __restrict__ wt) {
    int i = blockIdx.x * 256 + threadIdx.x;
    if (i >= WS_ELEMS) return;
    int kk = i % 40;
    int hp = (i / 40) % 144;
    int ck = i / (40 * 144);
    int sec = hp / 48, hh = hp % 48;
    int kc = ck * 32 + kk;
    float v = 0.f;
    if (kk < 32 && kc < CL && hh < HL) {
        const float* W = (sec == 0) ? Wk : (sec == 1) ? Wq : Wv;
        v = W[kc * HL + hh];
    }
    wt[i] = f2b(v);
}

template<int USEWS>
__global__ __launch_bounds__(256, 4)
void head_mfma(const float* __restrict__ x,
               const float* __restrict__ Wk, const float* __restrict__ Wq,
               const float* __restrict__ Wv,
               const u16* __restrict__ wt,
               float* __restrict__ out)
{
    extern __shared__ char lds[];
    char* L = lds;

    const int tid = threadIdx.x;
    const int wv  = tid >> 6;          // wave 0..3
    const int l   = tid & 63;
    const int lo  = l & 15;
    const int hi  = l >> 4;
    const int b   = blockIdx.x;
    const float* xb = x + (size_t)b * (TL * CL);

    // prologue: zero the 16-B gap (read by phase-S K-tail fragments, hi>=1)
    if (tid < 2) *(uint2*)(L + GAP_B + tid * 8) = make_uint2(0u, 0u);

    const int mt0 = wv * 2;            // this wave's 2 M-tiles

    // ---------------- phase K: [k|q|v] = x @ [Wk|Wq|Wv] (MFMA, streamed regs) ----------------
    #pragma unroll
    for (int m = 0; m < 2; ++m) {
        int trow = 16 * (mt0 + m) + lo;
        if (trow > TL - 1) trow = TL - 1;          // clamped rows produce discarded outputs
        const float* px = xb + trow * CL;

        f32x4 acc[9];
        #pragma unroll
        for (int n = 0; n < 9; ++n) acc[n] = (f32x4){0.f, 0.f, 0.f, 0.f};

        #pragma unroll
        for (int ks = 0; ks < 5; ++ks) {
            bf16x8 ah;
            if (ks < 4 || hi < 2) {                // k-cols 128..143 exist only for hi<2
                const float4 u = *(const float4*)(px + ks * 32 + hi * 8);
                const float4 v = *(const float4*)(px + ks * 32 + hi * 8 + 4);
                const float f[8] = {u.x, u.y, u.z, u.w, v.x, v.y, v.z, v.w};
                #pragma unroll
                for (int j = 0; j < 8; ++j) ah[j] = (short)f2b(f[j]);
            } else {
                ah = (bf16x8){0,0,0,0,0,0,0,0};
            }
            #pragma unroll
            for (int nt = 0; nt < 9; ++nt) {       // stream one W fragment at a time
                bf16x8 bfr;
                if (USEWS) {
                    bfr = *(const bf16x8*)(wt + (size_t)(ks * 144 + 16 * nt + lo) * 40 + hi * 8);
                } else {
                    int hp = 16 * nt + lo;
                    int sec = hp / 48, hh = hp % 48;
                    const float* W = (sec == 0) ? Wk : (sec == 1) ? Wq : Wv;
                    if (hh < HL && (ks < 4 || hi < 2)) {
                        #pragma unroll
                        for (int j = 0; j < 8; ++j)
                            bfr[j] = (short)f2b(W[(ks * 32 + hi * 8 + j) * HL + hh]);
                    } else bfr = (bf16x8){0,0,0,0,0,0,0,0};
                }
                acc[nt] = __builtin_amdgcn_mfma_f32_16x16x32_bf16(ah, bfr, acc[nt], 0, 0, 0);
            }
        }

        // D-writes: k (nt 0..2), q (nt 3..5), vT (nt 6..8). D layout: row=hi*4+r, col=lo.
        const int tb = 16 * (mt0 + m) + hi * 4;
        #pragma unroll
        for (int nt = 0; nt < 9; ++nt) {
            if (nt < 6) {
                u16* dst = (u16*)(L + ((nt < 3) ? 0 : Q_B));
                const int h = 16 * (nt - ((nt < 3) ? 0 : 3)) + lo;
                if (h < KQ_ST) {                   // cols 36..39 get acc==0 (W zero-padded)
                    #pragma unroll
                    for (int r = 0; r < 4; ++r) {
                        const int t = tb + r;
                        if (t < TL) dst[t * KQ_ST + h] = f2b(acc[nt][r]);
                    }
                }
            } else {
                const int hv = 16 * (nt - 6) + lo;
                if (hv < HL) {
                    union { u16 s[4]; uint2 d; } pk;
                    #pragma unroll
                    for (int r = 0; r < 4; ++r) pk.s[r] = f2b(acc[nt][r]);
                    int byt = VT_B + hv * 256 + tb * 2;
                    byt ^= (hv & 7) << 4;
                    *(uint2*)(L + byt) = pk.d;     // cols >=124 hold finite garbage; wei=0 there
                }
            }
        }
    }
    __syncthreads();

    // ---------------- phase S: scores = k @ q^T (MFMA) ----------------
    f32x4 sa[2][8];
    #pragma unroll
    for (int m = 0; m < 2; ++m)
        #pragma unroll
        for (int n = 0; n < 8; ++n) sa[m][n] = (f32x4){0.f, 0.f, 0.f, 0.f};

    #pragma unroll
    for (int ks = 0; ks < 2; ++ks) {
        bf16x8 af[2];
        #pragma unroll
        for (int m = 0; m < 2; ++m) {
            const int row = 16 * (mt0 + m) + lo;   // rows >=124 read garbage -> discarded rows
            const int byt = (ks == 0) ? (row * 80 + hi * 16)
                                      : ((hi == 0) ? (row * 80 + 64) : GAP_B);
            af[m] = *(const bf16x8*)(L + byt);
        }
        #pragma unroll
        for (int nt = 0; nt < 8; ++nt) {
            const int row = 16 * nt + lo;          // rows >=124 read garbage -> masked cols
            const int byt = (ks == 0) ? (Q_B + row * 80 + hi * 16)
                                      : ((hi == 0) ? (Q_B + row * 80 + 64) : GAP_B);
            const bf16x8 bq = *(const bf16x8*)(L + byt);
            #pragma unroll
            for (int m = 0; m < 2; ++m)
                sa[m][nt] = __builtin_amdgcn_mfma_f32_16x16x32_bf16(af[m], bq, sa[m][nt], 0, 0, 0);
        }
    }
    __syncthreads();   // all k/q reads done before wei overlays them

    // ---------------- softmax (causal), write wei (bf16, swizzled) ----------------
    const float scl = 1.0f / 12.0f;    // C^-0.5, C = 144 (faithful to reference)
    #pragma unroll
    for (int m = 0; m < 2; ++m) {
        #pragma unroll
        for (int r = 0; r < 4; ++r) {
            const int t = 16 * (mt0 + m) + hi * 4 + r;
            if (t < TL) {                          // uniform per 16-lane group
                float v8[8];
                float mx = -__builtin_inff();
                #pragma unroll
                for (int nt = 0; nt < 8; ++nt) {
                    const float sc = sa[m][nt][r] * scl;
                    v8[nt] = (16 * nt + lo <= t) ? sc : -__builtin_inff();
                    mx = fmaxf(mx, v8[nt]);
                }
                mx = fmaxf(mx, __shfl_xor(mx, 1));
                mx = fmaxf(mx, __shfl_xor(mx, 2));
                mx = fmaxf(mx, __shfl_xor(mx, 4));
                mx = fmaxf(mx, __shfl_xor(mx, 8));
                float e8[8], sum = 0.f;
                #pragma unroll
                for (int nt = 0; nt < 8; ++nt) { e8[nt] = __expf(v8[nt] - mx); sum += e8[nt]; }
                sum += __shfl_xor(sum, 1);
                sum += __shfl_xor(sum, 2);
                sum += __shfl_xor(sum, 4);
                sum += __shfl_xor(sum, 8);
                const float rs = __builtin_amdgcn_rcpf(sum);
                #pragma unroll
                for (int nt = 0; nt < 8; ++nt) {
                    int byt = t * 256 + (16 * nt + lo) * 2;
                    byt ^= (t & 7) << 4;
                    *(u16*)(L + byt) = f2b(e8[nt] * rs);
                }
            }
        }
    }
    __syncthreads();

    // ---------------- phase P: out = wei @ v (MFMA), direct global store ----------------
    f32x4 pa[2][3];
    #pragma unroll
    for (int m = 0; m < 2; ++m)
        #pragma unroll
        for (int n = 0; n < 3; ++n) pa[m][n] = (f32x4){0.f, 0.f, 0.f, 0.f};

    #pragma unroll
    for (int ks = 0; ks < 4; ++ks) {
        bf16x8 aw[2];
        #pragma unroll
        for (int m = 0; m < 2; ++m) {
            int row = 16 * (mt0 + m) + lo;
            if (row > TL - 1) row = TL - 1;        // clamp: rows 124..127 discarded
            int byt = row * 256 + (ks * 32 + hi * 8) * 2;
            byt ^= (row & 7) << 4;
            aw[m] = *(const bf16x8*)(L + byt);
        }
        #pragma unroll
        for (int nt = 0; nt < 3; ++nt) {
            const int h = 16 * nt + lo;
            int byt;
            if (h < HL) {
                byt = VT_B + h * 256 + (ks * 32 + hi * 8) * 2;
                byt ^= (h & 7) << 4;
            } else {
                byt = ZEROP_B;                     // broadcast 16 B of masked-zero wei row 0
            }
            const bf16x8 bv = *(const bf16x8*)(L + byt);
            #pragma unroll
            for (int m = 0; m < 2; ++m)
                pa[m][nt] = __builtin_amdgcn_mfma_f32_16x16x32_bf16(aw[m], bv, pa[m][nt], 0, 0, 0);
        }
    }

    float* ob = out + (size_t)b * (TL * HL);
    #pragma unroll
    for (int m = 0; m < 2; ++m) {
        #pragma unroll
        for (int nt = 0; nt < 3; ++nt) {
            #pragma unroll
            for (int r = 0; r < 4; ++r) {
                const int t = 16 * (mt0 + m) + hi * 4 + r;
                const int h = 16 * nt + lo;
                if (t < TL && h < HL) ob[t * HL + h] = pa[m][nt][r];
            }
        }
    }
}

extern "C" void kernel_launch(void* const* d_in, const int* in_sizes, int n_in,
                              void* d_out, int out_size, void* d_ws, size_t ws_size,
                              hipStream_t stream) {
    const float* x  = (const float*)d_in[0];
    const float* Wk = (const float*)d_in[1];
    const float* Wq = (const float*)d_in[2];
    const float* Wv = (const float*)d_in[3];
    float* out = (float*)d_out;
    const int B = in_sizes[0] / (TL * CL);   // 4096

    if (ws_size >= (size_t)WS_ELEMS * sizeof(u16)) {
        prepack_w<<<(WS_ELEMS + 255) / 256, 256, 0, stream>>>(Wk, Wq, Wv, (u16*)d_ws);
        head_mfma<1><<<dim3(B), dim3(256), LDS_BYTES, stream>>>(x, Wk, Wq, Wv, (const u16*)d_ws, out);
    } else {
        head_mfma<0><<<dim3(B), dim3(256), LDS_BYTES, stream>>>(x, Wk, Wq, Wv, nullptr, out);
    }
}

// Round 5
// 145.953 us; speedup vs baseline: 2.0237x; 2.0237x over previous
//
#include <hip/hip_runtime.h>

#define TL 124
#define CL 144
#define HL 36

typedef unsigned short u16;
typedef short bf16x8 __attribute__((ext_vector_type(8)));
typedef float f32x4  __attribute__((ext_vector_type(4)));

// LDS (bytes), 40960 total; 512-thread blocks, 3 blocks/CU (120 KiB):
//   k   @ 0     : bf16 [124][40]  = 9920   (cols 36..39 written as zeros)
//   gap @ 9920  : 16 B zeros (phase-S zero fragment for K-tail, hi>=1)
//   q   @ 9936  : bf16 [124][40]  = 9920   (ends 19856)
//   wei @ 0     : bf16 [124][128] = 31744  (overlays k/gap/q after scores barrier; XOR-swizzled)
//   vT  @ 31744 : bf16 [36][128]  = 9216   (vT[h][t], XOR-swizzled)
#define KQ_ST   40
#define GAP_B   9920
#define Q_B     9936
#define VT_B    31744
#define ZEROP_B 128     // wei row 0, cols 64..71: guaranteed masked-zero after softmax
#define LDS_BYTES 40960

// ws image: bf16 [5 kchunks][144 h_padded][40 kcols]; h_padded = 48*sec + hh,
// sec 0/1/2 = Wk/Wq/Wv, hh<36 valid else 0; kcol = 32*chunk + kk, kk<32 & kc<144 valid.
#define WS_ELEMS (5 * 144 * 40)

__device__ __forceinline__ u16 f2b(float f) {
    union { float f; unsigned u; } c; c.f = f;
    unsigned u = c.u;
    u += 0x7FFFu + ((u >> 16) & 1u);     // round-to-nearest-even
    return (u16)(u >> 16);
}

__global__ void prepack_w(const float* __restrict__ Wk, const float* __restrict__ Wq,
                          const float* __restrict__ Wv, u16* __restrict__ wt) {
    int i = blockIdx.x * 256 + threadIdx.x;
    if (i >= WS_ELEMS) return;
    int kk = i % 40;
    int hp = (i / 40) % 144;
    int ck = i / (40 * 144);
    int sec = hp / 48, hh = hp % 48;
    int kc = ck * 32 + kk;
    float v = 0.f;
    if (kk < 32 && kc < CL && hh < HL) {
        const float* W = (sec == 0) ? Wk : (sec == 1) ? Wq : Wv;
        v = W[kc * HL + hh];
    }
    wt[i] = f2b(v);
}

template<int USEWS>
__global__ __launch_bounds__(512, 6)
void head_mfma(const float* __restrict__ x,
               const float* __restrict__ Wk, const float* __restrict__ Wq,
               const float* __restrict__ Wv,
               const u16* __restrict__ wt,
               float* __restrict__ out)
{
    extern __shared__ char lds[];
    char* L = lds;

    const int tid = threadIdx.x;
    const int wv  = tid >> 6;          // wave 0..7 = this wave's M-tile
    const int l   = tid & 63;
    const int lo  = l & 15;
    const int hi  = l >> 4;
    const int b   = blockIdx.x;
    const float* xb = x + (size_t)b * (TL * CL);

    // prologue: zero the 16-B gap (read by phase-S K-tail fragments, hi>=1)
    if (tid < 2) *(uint2*)(L + GAP_B + tid * 8) = make_uint2(0u, 0u);

    // ---------------- phase K: [k|q|v] = x @ [Wk|Wq|Wv] (MFMA, 1 M-tile/wave) ----------------
    {
        int trow = 16 * wv + lo;
        if (trow > TL - 1) trow = TL - 1;          // clamped rows produce discarded outputs
        const float* px = xb + trow * CL;

        f32x4 acc[9];
        #pragma unroll
        for (int n = 0; n < 9; ++n) acc[n] = (f32x4){0.f, 0.f, 0.f, 0.f};

        #pragma unroll
        for (int ks = 0; ks < 5; ++ks) {
            bf16x8 ah;
            if (ks < 4 || hi < 2) {                // k-cols 128..143 exist only for hi<2
                const float4 u = *(const float4*)(px + ks * 32 + hi * 8);
                const float4 v = *(const float4*)(px + ks * 32 + hi * 8 + 4);
                const float f[8] = {u.x, u.y, u.z, u.w, v.x, v.y, v.z, v.w};
                #pragma unroll
                for (int j = 0; j < 8; ++j) ah[j] = (short)f2b(f[j]);
            } else {
                ah = (bf16x8){0,0,0,0,0,0,0,0};
            }
            #pragma unroll
            for (int nt = 0; nt < 9; ++nt) {
                bf16x8 bfr;
                if (USEWS) {
                    bfr = *(const bf16x8*)(wt + (size_t)(ks * 144 + 16 * nt + lo) * 40 + hi * 8);
                } else {
                    int hp = 16 * nt + lo;
                    int sec = hp / 48, hh = hp % 48;
                    const float* W = (sec == 0) ? Wk : (sec == 1) ? Wq : Wv;
                    if (hh < HL && (ks < 4 || hi < 2)) {
                        #pragma unroll
                        for (int j = 0; j < 8; ++j)
                            bfr[j] = (short)f2b(W[(ks * 32 + hi * 8 + j) * HL + hh]);
                    } else bfr = (bf16x8){0,0,0,0,0,0,0,0};
                }
                acc[nt] = __builtin_amdgcn_mfma_f32_16x16x32_bf16(ah, bfr, acc[nt], 0, 0, 0);
            }
        }

        // D-writes: k (nt 0..2), q (nt 3..5), vT (nt 6..8). D layout: row=hi*4+r, col=lo.
        const int tb = 16 * wv + hi * 4;
        #pragma unroll
        for (int nt = 0; nt < 9; ++nt) {
            if (nt < 6) {
                u16* dst = (u16*)(L + ((nt < 3) ? 0 : Q_B));
                const int h = 16 * (nt - ((nt < 3) ? 0 : 3)) + lo;
                if (h < KQ_ST) {                   // cols 36..39 get acc==0 (W zero-padded)
                    #pragma unroll
                    for (int r = 0; r < 4; ++r) {
                        const int t = tb + r;
                        if (t < TL) dst[t * KQ_ST + h] = f2b(acc[nt][r]);
                    }
                }
            } else {
                const int hv = 16 * (nt - 6) + lo;
                if (hv < HL) {
                    union { u16 s[4]; uint2 d; } pk;
                    #pragma unroll
                    for (int r = 0; r < 4; ++r) pk.s[r] = f2b(acc[nt][r]);
                    int byt = VT_B + hv * 256 + tb * 2;
                    byt ^= (hv & 7) << 4;
                    *(uint2*)(L + byt) = pk.d;     // cols >=124 hold finite garbage; wei=0 there
                }
            }
        }
    }
    __syncthreads();

    // ---------------- phase S: scores = k @ q^T (MFMA, 1 M-tile/wave) ----------------
    f32x4 sa[8];
    #pragma unroll
    for (int n = 0; n < 8; ++n) sa[n] = (f32x4){0.f, 0.f, 0.f, 0.f};

    #pragma unroll
    for (int ks = 0; ks < 2; ++ks) {
        const int arow = 16 * wv + lo;             // rows >=124 read in-LDS garbage -> discarded
        const int abyt = (ks == 0) ? (arow * 80 + hi * 16)
                                   : ((hi == 0) ? (arow * 80 + 64) : GAP_B);
        const bf16x8 af = *(const bf16x8*)(L + abyt);
        #pragma unroll
        for (int nt = 0; nt < 8; ++nt) {
            const int row = 16 * nt + lo;          // rows >=124 garbage -> cols always masked
            const int byt = (ks == 0) ? (Q_B + row * 80 + hi * 16)
                                      : ((hi == 0) ? (Q_B + row * 80 + 64) : GAP_B);
            const bf16x8 bq = *(const bf16x8*)(L + byt);
            sa[nt] = __builtin_amdgcn_mfma_f32_16x16x32_bf16(af, bq, sa[nt], 0, 0, 0);
        }
    }
    __syncthreads();   // all k/q reads done before wei overlays them

    // ---------------- softmax (causal), write wei (bf16, swizzled) ----------------
    const float scl = 1.0f / 12.0f;    // C^-0.5, C = 144 (faithful to reference)
    #pragma unroll
    for (int r = 0; r < 4; ++r) {
        const int t = 16 * wv + hi * 4 + r;
        if (t < TL) {                              // uniform per 16-lane group
            float v8[8];
            float mx = -__builtin_inff();
            #pragma unroll
            for (int nt = 0; nt < 8; ++nt) {
                const float sc = sa[nt][r] * scl;
                v8[nt] = (16 * nt + lo <= t) ? sc : -__builtin_inff();
                mx = fmaxf(mx, v8[nt]);
            }
            mx = fmaxf(mx, __shfl_xor(mx, 1));
            mx = fmaxf(mx, __shfl_xor(mx, 2));
            mx = fmaxf(mx, __shfl_xor(mx, 4));
            mx = fmaxf(mx, __shfl_xor(mx, 8));
            float e8[8], sum = 0.f;
            #pragma unroll
            for (int nt = 0; nt < 8; ++nt) { e8[nt] = __expf(v8[nt] - mx); sum += e8[nt]; }
            sum += __shfl_xor(sum, 1);
            sum += __shfl_xor(sum, 2);
            sum += __shfl_xor(sum, 4);
            sum += __shfl_xor(sum, 8);
            const float rs = __builtin_amdgcn_rcpf(sum);
            #pragma unroll
            for (int nt = 0; nt < 8; ++nt) {
                int byt = t * 256 + (16 * nt + lo) * 2;
                byt ^= (t & 7) << 4;
                *(u16*)(L + byt) = f2b(e8[nt] * rs);
            }
        }
    }
    __syncthreads();

    // ---------------- phase P: out = wei @ v (MFMA), direct global store ----------------
    f32x4 pa[3];
    #pragma unroll
    for (int n = 0; n < 3; ++n) pa[n] = (f32x4){0.f, 0.f, 0.f, 0.f};

    #pragma unroll
    for (int ks = 0; ks < 4; ++ks) {
        int row = 16 * wv + lo;
        if (row > TL - 1) row = TL - 1;            // clamp: rows 124..127 discarded
        int abyt = row * 256 + (ks * 32 + hi * 8) * 2;
        abyt ^= (row & 7) << 4;
        const bf16x8 aw = *(const bf16x8*)(L + abyt);
        #pragma unroll
        for (int nt = 0; nt < 3; ++nt) {
            const int h = 16 * nt + lo;
            int byt;
            if (h < HL) {
                byt = VT_B + h * 256 + (ks * 32 + hi * 8) * 2;
                byt ^= (h & 7) << 4;
            } else {
                byt = ZEROP_B;                     // broadcast 16 B of masked-zero wei row 0
            }
            const bf16x8 bv = *(const bf16x8*)(L + byt);
            pa[nt] = __builtin_amdgcn_mfma_f32_16x16x32_bf16(aw, bv, pa[nt], 0, 0, 0);
        }
    }

    float* ob = out + (size_t)b * (TL * HL);
    #pragma unroll
    for (int nt = 0; nt < 3; ++nt) {
        #pragma unroll
        for (int r = 0; r < 4; ++r) {
            const int t = 16 * wv + hi * 4 + r;
            const int h = 16 * nt + lo;
            if (t < TL && h < HL) ob[t * HL + h] = pa[nt][r];
        }
    }
}

extern "C" void kernel_launch(void* const* d_in, const int* in_sizes, int n_in,
                              void* d_out, int out_size, void* d_ws, size_t ws_size,
                              hipStream_t stream) {
    const float* x  = (const float*)d_in[0];
    const float* Wk = (const float*)d_in[1];
    const float* Wq = (const float*)d_in[2];
    const float* Wv = (const float*)d_in[3];
    float* out = (float*)d_out;
    const int B = in_sizes[0] / (TL * CL);   // 4096

    if (ws_size >= (size_t)WS_ELEMS * sizeof(u16)) {
        prepack_w<<<(WS_ELEMS + 255) / 256, 256, 0, stream>>>(Wk, Wq, Wv, (u16*)d_ws);
        head_mfma<1><<<dim3(B), dim3(512), LDS_BYTES, stream>>>(x, Wk, Wq, Wv, (const u16*)d_ws, out);
    } else {
        head_mfma<0><<<dim3(B), dim3(512), LDS_BYTES, stream>>>(x, Wk, Wq, Wv, nullptr, out);
    }
}

// Round 6
// 137.489 us; speedup vs baseline: 2.1482x; 1.0616x over previous
//
#include <hip/hip_runtime.h>

#define TL 124
#define CL 144
#define HL 36

typedef unsigned short u16;
typedef short bf16x8 __attribute__((ext_vector_type(8)));
typedef float f32x4  __attribute__((ext_vector_type(4)));

// LDS (bytes), 40960 total; 512-thread blocks:
//   k   @ 0     : bf16 [124][40]  = 9920   (cols 36..39 zeroed in prologue)
//   gap @ 9920  : 16 B zeros (phase-S zero fragment for K-tail, hi>=1)
//   q   @ 9936  : bf16 [124][40]  = 9920   (ends 19856; cols 36..39 zeroed)
//   wei @ 0     : bf16 [124][128] = 31744  (overlays k/gap/q after scores barrier; XOR-swizzled)
//   vT  @ 31744 : bf16 [36][128]  = 9216   (vT[h][t], XOR-swizzled)
#define KQ_ST   40
#define GAP_B   9920
#define Q_B     9936
#define VT_B    31744
#define ZEROP_B 128     // wei row 0, cols 64..71: masked-zero after softmax
#define LDS_BYTES 40960

// ws image: bf16 [5 kchunks][112 hp][40 kcols]; hp<36: Wk[:,hp], hp<72: Wq[:,hp-36],
// hp<108: Wv[:,hp-72], hp>=108: 0. kcol = 32*chunk + kk, valid iff kk<32 && kc<144.
#define WS_ELEMS (5 * 112 * 40)

__device__ __forceinline__ u16 f2b(float f) {
    union { float f; unsigned u; } c; c.f = f;
    unsigned u = c.u;
    u += 0x7FFFu + ((u >> 16) & 1u);     // round-to-nearest-even
    return (u16)(u >> 16);
}

__device__ __forceinline__ unsigned cvtpk(float a, float b) {   // [bf16(a) lo | bf16(b) hi]
    unsigned r;
    asm("v_cvt_pk_bf16_f32 %0, %1, %2" : "=v"(r) : "v"(a), "v"(b));
    return r;
}

__global__ void prepack_w(const float* __restrict__ Wk, const float* __restrict__ Wq,
                          const float* __restrict__ Wv, u16* __restrict__ wt) {
    int i = blockIdx.x * 256 + threadIdx.x;
    if (i >= WS_ELEMS) return;
    int kk = i % 40;
    int hp = (i / 40) % 112;
    int ck = i / (40 * 112);
    int kc = ck * 32 + kk;
    float v = 0.f;
    if (kk < 32 && kc < CL && hp < 108) {
        int sec = (hp < 36) ? 0 : ((hp < 72) ? 1 : 2);
        int h = hp - sec * 36;
        const float* W = (sec == 0) ? Wk : (sec == 1) ? Wq : Wv;
        v = W[kc * HL + h];
    }
    wt[i] = f2b(v);
}

template<int USEWS>
__global__ __launch_bounds__(512, 6)
void head_mfma(const float* __restrict__ x,
               const float* __restrict__ Wk, const float* __restrict__ Wq,
               const float* __restrict__ Wv,
               const u16* __restrict__ wt,
               float* __restrict__ out)
{
    extern __shared__ char lds[];
    char* L = lds;

    const int tid = threadIdx.x;
    const int wv  = tid >> 6;          // wave 0..7 = this wave's M-tile
    const int l   = tid & 63;
    const int lo  = l & 15;
    const int hi  = l >> 4;
    const int b   = blockIdx.x;
    const float* xb = x + (size_t)b * (TL * CL);

    // prologue: zero gap + k/q cols 36..39 (never written by packed-W D-writes,
    // but read by phase-S ks=1 fragments)
    if (tid < 2) *(uint2*)(L + GAP_B + tid * 8) = make_uint2(0u, 0u);
    for (int i = tid; i < 248; i += 512) {
        const int buf = i & 1, t = i >> 1;
        *(uint2*)(L + (buf ? Q_B : 0) + t * 80 + 72) = make_uint2(0u, 0u);
    }

    // ---------------- phase K: [k|q|v] = x @ [Wk|Wq|Wv] (MFMA, packed 7 tiles) ----------------
    {
        int trow = 16 * wv + lo;
        if (trow > TL - 1) trow = TL - 1;          // clamped rows produce discarded outputs
        const float* px = xb + trow * CL;

        f32x4 acc[7];
        #pragma unroll
        for (int n = 0; n < 7; ++n) acc[n] = (f32x4){0.f, 0.f, 0.f, 0.f};

        #pragma unroll
        for (int ks = 0; ks < 5; ++ks) {
            bf16x8 ah;
            if (ks < 4 || hi < 2) {                // k-cols 128..143 exist only for hi<2
                const float4 u = *(const float4*)(px + ks * 32 + hi * 8);
                const float4 v = *(const float4*)(px + ks * 32 + hi * 8 + 4);
                union { unsigned w[4]; bf16x8 h8; } cc;
                cc.w[0] = cvtpk(u.x, u.y);
                cc.w[1] = cvtpk(u.z, u.w);
                cc.w[2] = cvtpk(v.x, v.y);
                cc.w[3] = cvtpk(v.z, v.w);
                ah = cc.h8;
            } else {
                ah = (bf16x8){0,0,0,0,0,0,0,0};
            }
            #pragma unroll
            for (int nt = 0; nt < 7; ++nt) {
                bf16x8 bfr;
                if (USEWS) {
                    bfr = *(const bf16x8*)(wt + (size_t)(ks * 112 + 16 * nt + lo) * 40 + hi * 8);
                } else {
                    const int hp = 16 * nt + lo;
                    if (hp < 108 && (ks < 4 || hi < 2)) {
                        const int sec = (hp < 36) ? 0 : ((hp < 72) ? 1 : 2);
                        const int h = hp - sec * 36;
                        const float* W = (sec == 0) ? Wk : (sec == 1) ? Wq : Wv;
                        #pragma unroll
                        for (int j = 0; j < 8; ++j)
                            bfr[j] = (short)f2b(W[(ks * 32 + hi * 8 + j) * HL + h]);
                    } else bfr = (bf16x8){0,0,0,0,0,0,0,0};
                }
                acc[nt] = __builtin_amdgcn_mfma_f32_16x16x32_bf16(ah, bfr, acc[nt], 0, 0, 0);
            }
        }

        // D-writes, per-lane routing: hp<36 -> k, <72 -> q, <108 -> vT. D row=hi*4+r, col=lo.
        const int tb = 16 * wv + hi * 4;
        #pragma unroll
        for (int nt = 0; nt < 7; ++nt) {
            const int hp = 16 * nt + lo;
            const unsigned w01 = cvtpk(acc[nt][0], acc[nt][1]);
            const unsigned w23 = cvtpk(acc[nt][2], acc[nt][3]);
            if (hp < 72) {
                u16* dst = (u16*)(L + ((hp < 36) ? 0 : Q_B));
                const int h = (hp < 36) ? hp : hp - 36;
                if (tb + 0 < TL) dst[(tb + 0) * KQ_ST + h] = (u16)(w01 & 0xffffu);
                if (tb + 1 < TL) dst[(tb + 1) * KQ_ST + h] = (u16)(w01 >> 16);
                if (tb + 2 < TL) dst[(tb + 2) * KQ_ST + h] = (u16)(w23 & 0xffffu);
                if (tb + 3 < TL) dst[(tb + 3) * KQ_ST + h] = (u16)(w23 >> 16);
            } else if (hp < 108) {
                const int hv = hp - 72;
                int byt = VT_B + hv * 256 + tb * 2;
                byt ^= (hv & 7) << 4;
                *(uint2*)(L + byt) = make_uint2(w01, w23);   // t-cols >=124: finite garbage, wei=0 there
            }
        }
    }
    __syncthreads();

    // ---------------- phase S (transposed): D[s][t] = q[s] . k[t] ----------------
    f32x4 sa[8];
    #pragma unroll
    for (int n = 0; n < 8; ++n) sa[n] = (f32x4){0.f, 0.f, 0.f, 0.f};

    #pragma unroll
    for (int ks = 0; ks < 2; ++ks) {
        const int krow = 16 * wv + lo;             // rows >=124 read garbage -> t-cols discarded
        const int kbyt = (ks == 0) ? (krow * 80 + hi * 16)
                                   : ((hi == 0) ? (krow * 80 + 64) : GAP_B);
        const bf16x8 bk = *(const bf16x8*)(L + kbyt);
        #pragma unroll
        for (int nt = 0; nt < 8; ++nt) {
            const int qrow = 16 * nt + lo;         // rows >=124 garbage -> s always masked
            const int qbyt = (ks == 0) ? (Q_B + qrow * 80 + hi * 16)
                                       : ((hi == 0) ? (Q_B + qrow * 80 + 64) : GAP_B);
            const bf16x8 aq = *(const bf16x8*)(L + qbyt);
            sa[nt] = __builtin_amdgcn_mfma_f32_16x16x32_bf16(aq, bk, sa[nt], 0, 0, 0);
        }
    }
    __syncthreads();   // all k/q reads done before wei overlays them

    // ---------------- softmax: lane owns col t = 16*wv+lo; rows s = 16*nt+4*hi+r ----------------
    {
        const float scl = 1.0f / 12.0f;            // C^-0.5, C = 144 (faithful to reference)
        const int t = 16 * wv + lo;
        float e[8][4];
        float mx = -__builtin_inff();
        #pragma unroll
        for (int nt = 0; nt < 8; ++nt)
            #pragma unroll
            for (int r = 0; r < 4; ++r) {
                const int s = 16 * nt + 4 * hi + r;
                const float v = sa[nt][r] * scl;
                e[nt][r] = (s <= t) ? v : -__builtin_inff();
                mx = fmaxf(mx, e[nt][r]);
            }
        mx = fmaxf(mx, __shfl_xor(mx, 16));        // combine the 4 lanes sharing col t
        mx = fmaxf(mx, __shfl_xor(mx, 32));
        float sum = 0.f;
        #pragma unroll
        for (int nt = 0; nt < 8; ++nt)
            #pragma unroll
            for (int r = 0; r < 4; ++r) {
                const float ex = __expf(e[nt][r] - mx);
                e[nt][r] = ex;
                sum += ex;
            }
        sum += __shfl_xor(sum, 16);
        sum += __shfl_xor(sum, 32);
        const float rs = __builtin_amdgcn_rcpf(sum);
        if (t < TL) {                              // t>=124 lanes would overwrite vT
            #pragma unroll
            for (int nt = 0; nt < 8; ++nt) {
                const unsigned w01 = cvtpk(e[nt][0] * rs, e[nt][1] * rs);
                const unsigned w23 = cvtpk(e[nt][2] * rs, e[nt][3] * rs);
                int byt = t * 256 + (16 * nt + 4 * hi) * 2;
                byt ^= (t & 7) << 4;
                *(uint2*)(L + byt) = make_uint2(w01, w23);
            }
        }
    }
    __syncthreads();

    // ---------------- phase P: out = wei @ v (MFMA), direct global store ----------------
    f32x4 pa[3];
    #pragma unroll
    for (int n = 0; n < 3; ++n) pa[n] = (f32x4){0.f, 0.f, 0.f, 0.f};

    #pragma unroll
    for (int ks = 0; ks < 4; ++ks) {
        int row = 16 * wv + lo;
        if (row > TL - 1) row = TL - 1;            // clamp: rows 124..127 unwritten/discarded
        int abyt = row * 256 + (ks * 32 + hi * 8) * 2;
        abyt ^= (row & 7) << 4;
        const bf16x8 aw = *(const bf16x8*)(L + abyt);
        #pragma unroll
        for (int nt = 0; nt < 3; ++nt) {
            const int h = 16 * nt + lo;
            int byt;
            if (h < HL) {
                byt = VT_B + h * 256 + (ks * 32 + hi * 8) * 2;
                byt ^= (h & 7) << 4;
            } else {
                byt = ZEROP_B;                     // 16 B of masked-zero wei row 0
            }
            const bf16x8 bv = *(const bf16x8*)(L + byt);
            pa[nt] = __builtin_amdgcn_mfma_f32_16x16x32_bf16(aw, bv, pa[nt], 0, 0, 0);
        }
    }

    float* ob = out + (size_t)b * (TL * HL);
    #pragma unroll
    for (int nt = 0; nt < 3; ++nt) {
        #pragma unroll
        for (int r = 0; r < 4; ++r) {
            const int t = 16 * wv + hi * 4 + r;
            const int h = 16 * nt + lo;
            if (t < TL && h < HL) ob[t * HL + h] = pa[nt][r];
        }
    }
}

extern "C" void kernel_launch(void* const* d_in, const int* in_sizes, int n_in,
                              void* d_out, int out_size, void* d_ws, size_t ws_size,
                              hipStream_t stream) {
    const float* x  = (const float*)d_in[0];
    const float* Wk = (const float*)d_in[1];
    const float* Wq = (const float*)d_in[2];
    const float* Wv = (const float*)d_in[3];
    float* out = (float*)d_out;
    const int B = in_sizes[0] / (TL * CL);   // 4096

    if (ws_size >= (size_t)WS_ELEMS * sizeof(u16)) {
        prepack_w<<<(WS_ELEMS + 255) / 256, 256, 0, stream>>>(Wk, Wq, Wv, (u16*)d_ws);
        head_mfma<1><<<dim3(B), dim3(512), LDS_BYTES, stream>>>(x, Wk, Wq, Wv, (const u16*)d_ws, out);
    } else {
        head_mfma<0><<<dim3(B), dim3(512), LDS_BYTES, stream>>>(x, Wk, Wq, Wv, nullptr, out);
    }
}

// Round 7
// 136.460 us; speedup vs baseline: 2.1644x; 1.0075x over previous
//
#include <hip/hip_runtime.h>

#define TL 124
#define CL 144
#define HL 36

typedef unsigned short u16;
typedef short bf16x8 __attribute__((ext_vector_type(8)));
typedef float f32x4  __attribute__((ext_vector_type(4)));

// LDS (bytes), 40960 total; 512-thread blocks, 3 blocks/CU (120 KiB):
//   k   @ 0     : bf16 [128][40] = 10240  (cols 36..39 zeroed; rows >=124 finite garbage)
//   gap @ 10240 : 16 B zeros (phase-S K-tail fragment for hi>=1)
//   q   @ 10256 : bf16 [128][40] = 10240  (ends 20496)
//   wei @ 0     : bf16 [124][128] = 31744 (overlays k/gap/q after S-barrier; XOR-swizzled; UNNORMALIZED)
//   vT  @ 31744 : bf16 [36][128] = 9216   (vT[h][t], XOR-swizzled)
#define KQ_ST   40
#define GAP_B   10240
#define Q_B     10256
#define VT_B    31744
#define ZEROP_B 128     // wei row 0, cols 64..71: masked-zero
#define LDS_BYTES 40960

// k is pre-scaled by log2(e)/12 so scores are in log2 domain: softmax uses raw v_exp_f32 (2^x).
#define SCL_K 0.12022458674074693f

// ws image: bf16 [5 kchunks][112 hp][40 kcols]; hp<36: Wk, hp<72: Wq, hp<108: Wv, else 0.
#define WS_ELEMS (5 * 112 * 40)

__device__ __forceinline__ u16 f2b(float f) {
    union { float f; unsigned u; } c; c.f = f;
    unsigned u = c.u;
    u += 0x7FFFu + ((u >> 16) & 1u);     // round-to-nearest-even
    return (u16)(u >> 16);
}

__device__ __forceinline__ unsigned cvtpk(float a, float b) {   // [bf16(a) lo | bf16(b) hi]
    unsigned r;
    asm("v_cvt_pk_bf16_f32 %0, %1, %2" : "=v"(r) : "v"(a), "v"(b));
    return r;
}

__device__ __forceinline__ float vexp2(float x) {               // 2^x
    float r;
    asm("v_exp_f32 %0, %1" : "=v"(r) : "v"(x));
    return r;
}

__global__ void prepack_w(const float* __restrict__ Wk, const float* __restrict__ Wq,
                          const float* __restrict__ Wv, u16* __restrict__ wt) {
    int i = blockIdx.x * 256 + threadIdx.x;
    if (i >= WS_ELEMS) return;
    int kk = i % 40;
    int hp = (i / 40) % 112;
    int ck = i / (40 * 112);
    int kc = ck * 32 + kk;
    float v = 0.f;
    if (kk < 32 && kc < CL && hp < 108) {
        int sec = (hp < 36) ? 0 : ((hp < 72) ? 1 : 2);
        int h = hp - sec * 36;
        const float* W = (sec == 0) ? Wk : (sec == 1) ? Wq : Wv;
        v = W[kc * HL + h];
    }
    wt[i] = f2b(v);
}

template<int USEWS>
__global__ __launch_bounds__(512, 6)
void head_mfma(const float* __restrict__ x,
               const float* __restrict__ Wk, const float* __restrict__ Wq,
               const float* __restrict__ Wv,
               const u16* __restrict__ wt,
               float* __restrict__ out)
{
    extern __shared__ char lds[];
    char* L = lds;

    const int tid = threadIdx.x;
    const int wv  = tid >> 6;          // wave 0..7 = M-tile
    const int l   = tid & 63;
    const int lo  = l & 15;
    const int hi  = l >> 4;
    const int b   = blockIdx.x;
    const float* xb = x + (size_t)b * (TL * CL);

    // prologue: zero gap + k/q cols 36..39 for all 128 rows (read by phase-S ks=1 fragments)
    if (tid < 2) *(uint2*)(L + GAP_B + tid * 8) = make_uint2(0u, 0u);
    for (int i = tid; i < 256; i += 512) {
        const int buf = i & 1, t = i >> 1;
        *(uint2*)(L + (buf ? Q_B : 0) + t * 80 + 72) = make_uint2(0u, 0u);
    }

    // ---------------- phase K: [k|q|v] = x @ [Wk|Wq|Wv] (MFMA, pipelined loads) ----------------
    {
        int trow = 16 * wv + lo;
        if (trow > TL - 1) trow = TL - 1;          // clamp; clamped rows' outputs are discarded
        const float* px = xb + trow * CL;

        f32x4 acc[7];
        #pragma unroll
        for (int n = 0; n < 7; ++n) acc[n] = (f32x4){0.f, 0.f, 0.f, 0.f};

        // x pipeline: current chunk in (cu,cv), next prefetched into (nu,nv).
        // Tail chunk (ks=4, hi>=2) reads past the row into the next row — in-bounds
        // globally (trow<=123, worst offset < 4096*124*144) — and is masked to zero.
        float4 cu = *(const float4*)(px + hi * 8);
        float4 cv = *(const float4*)(px + hi * 8 + 4);

        #pragma unroll
        for (int ks = 0; ks < 5; ++ks) {
            float4 nu, nv;
            if (ks < 4) {
                const float* nx = px + (ks + 1) * 32 + hi * 8;
                nu = *(const float4*)(nx);
                nv = *(const float4*)(nx + 4);
            }
            union { unsigned w[4]; bf16x8 h8; } cc;
            cc.w[0] = cvtpk(cu.x, cu.y);
            cc.w[1] = cvtpk(cu.z, cu.w);
            cc.w[2] = cvtpk(cv.x, cv.y);
            cc.w[3] = cvtpk(cv.z, cv.w);
            if (ks == 4 && hi >= 2) { cc.w[0] = 0; cc.w[1] = 0; cc.w[2] = 0; cc.w[3] = 0; }
            const bf16x8 ah = cc.h8;

            bf16x8 bfr[7];
            #pragma unroll
            for (int nt = 0; nt < 7; ++nt) {       // batch: 7 loads in flight before MFMAs
                if (USEWS) {
                    bfr[nt] = *(const bf16x8*)(wt + (size_t)(ks * 112 + 16 * nt + lo) * 40 + hi * 8);
                } else {
                    const int hp = 16 * nt + lo;
                    if (hp < 108 && (ks < 4 || hi < 2)) {
                        const int sec = (hp < 36) ? 0 : ((hp < 72) ? 1 : 2);
                        const int h = hp - sec * 36;
                        const float* W = (sec == 0) ? Wk : (sec == 1) ? Wq : Wv;
                        #pragma unroll
                        for (int j = 0; j < 8; ++j)
                            bfr[nt][j] = (short)f2b(W[(ks * 32 + hi * 8 + j) * HL + h]);
                    } else bfr[nt] = (bf16x8){0,0,0,0,0,0,0,0};
                }
            }
            #pragma unroll
            for (int nt = 0; nt < 7; ++nt)
                acc[nt] = __builtin_amdgcn_mfma_f32_16x16x32_bf16(ah, bfr[nt], acc[nt], 0, 0, 0);
            cu = nu; cv = nv;
        }

        // D-writes (unconditional; rows padded to 128): k gets SCL_K folded in.
        const int tb = 16 * wv + hi * 4;
        #pragma unroll
        for (int nt = 0; nt < 7; ++nt) {
            const int hp = 16 * nt + lo;
            float s0 = acc[nt][0], s1 = acc[nt][1], s2 = acc[nt][2], s3 = acc[nt][3];
            if (nt < 3) {                          // only nt 0..2 contain k lanes (hp<36)
                const float m = (hp < 36) ? SCL_K : 1.0f;
                s0 *= m; s1 *= m; s2 *= m; s3 *= m;
            }
            const unsigned w01 = cvtpk(s0, s1);
            const unsigned w23 = cvtpk(s2, s3);
            if (hp < 72) {
                u16* dst = (u16*)(L + ((hp < 36) ? 0 : Q_B));
                const int h = (hp < 36) ? hp : hp - 36;
                dst[(tb + 0) * KQ_ST + h] = (u16)(w01 & 0xffffu);
                dst[(tb + 1) * KQ_ST + h] = (u16)(w01 >> 16);
                dst[(tb + 2) * KQ_ST + h] = (u16)(w23 & 0xffffu);
                dst[(tb + 3) * KQ_ST + h] = (u16)(w23 >> 16);
            } else if (hp < 108) {
                const int hv = hp - 72;
                int byt = VT_B + hv * 256 + tb * 2;
                byt ^= (hv & 7) << 4;
                *(uint2*)(L + byt) = make_uint2(w01, w23);   // t-cols >=124: finite garbage, wei=0 there
            }
        }
    }
    __syncthreads();

    // ---------------- phase S (transposed): D[s][t] = q[s] . k~[t] (k~ pre-scaled) ----------------
    f32x4 sa[8];
    #pragma unroll
    for (int n = 0; n < 8; ++n) sa[n] = (f32x4){0.f, 0.f, 0.f, 0.f};

    {
        const int krow = 16 * wv + lo;             // rows >=124: finite garbage -> t-cols discarded
        const bf16x8 bk0 = *(const bf16x8*)(L + krow * 80 + hi * 16);
        const bf16x8 bk1 = *(const bf16x8*)(L + ((hi == 0) ? (krow * 80 + 64) : GAP_B));
        bf16x8 aq[8];
        #pragma unroll
        for (int nt = 0; nt < 8; ++nt)             // batch 8 loads
            aq[nt] = *(const bf16x8*)(L + Q_B + (16 * nt + lo) * 80 + hi * 16);
        #pragma unroll
        for (int nt = 0; nt < 8; ++nt)
            sa[nt] = __builtin_amdgcn_mfma_f32_16x16x32_bf16(aq[nt], bk0, sa[nt], 0, 0, 0);
        #pragma unroll
        for (int nt = 0; nt < 8; ++nt)
            aq[nt] = *(const bf16x8*)(L + ((hi == 0) ? (Q_B + (16 * nt + lo) * 80 + 64) : GAP_B));
        #pragma unroll
        for (int nt = 0; nt < 8; ++nt)
            sa[nt] = __builtin_amdgcn_mfma_f32_16x16x32_bf16(aq[nt], bk1, sa[nt], 0, 0, 0);
    }
    __syncthreads();   // all k/q reads done before wei overlays them

    // ---------------- softmax (log2 domain): lane owns col t; rows s = 16*nt+4*hi+r ----------------
    float rs;
    {
        const int t = 16 * wv + lo;
        float p[8][4];
        float mx = -__builtin_inff();
        #pragma unroll
        for (int nt = 0; nt < 8; ++nt)
            #pragma unroll
            for (int r = 0; r < 4; ++r) {
                const int s = 16 * nt + 4 * hi + r;
                p[nt][r] = (s <= t) ? sa[nt][r] : -__builtin_inff();
                mx = fmaxf(mx, p[nt][r]);
            }
        mx = fmaxf(mx, __shfl_xor(mx, 16));        // 4 lanes share col t
        mx = fmaxf(mx, __shfl_xor(mx, 32));
        float sum = 0.f;
        #pragma unroll
        for (int nt = 0; nt < 8; ++nt)
            #pragma unroll
            for (int r = 0; r < 4; ++r) {
                const float ex = vexp2(p[nt][r] - mx);   // -inf -> 0
                p[nt][r] = ex;
                sum += ex;
            }
        sum += __shfl_xor(sum, 16);
        sum += __shfl_xor(sum, 32);
        rs = __builtin_amdgcn_rcpf(sum);           // sum >= 1 (max element contributes 1)
        if (t < TL) {                              // t>=124 lanes would overwrite vT
            #pragma unroll
            for (int nt = 0; nt < 8; ++nt) {
                const unsigned w01 = cvtpk(p[nt][0], p[nt][1]);   // UNNORMALIZED wei
                const unsigned w23 = cvtpk(p[nt][2], p[nt][3]);
                int byt = t * 256 + (16 * nt + 4 * hi) * 2;
                byt ^= (t & 7) << 4;
                *(uint2*)(L + byt) = make_uint2(w01, w23);
            }
        }
    }
    __syncthreads();

    // ---------------- phase P: out = wei @ v (MFMA), normalize by 1/sum at f32 epilogue ----------------
    f32x4 pa[3];
    #pragma unroll
    for (int n = 0; n < 3; ++n) pa[n] = (f32x4){0.f, 0.f, 0.f, 0.f};

    {
        int wrow = 16 * wv + lo;
        if (wrow > TL - 1) wrow = TL - 1;          // clamp: rows 124..127 discarded
        #pragma unroll
        for (int ks = 0; ks < 4; ++ks) {
            int abyt = wrow * 256 + (ks * 32 + hi * 8) * 2;
            abyt ^= (wrow & 7) << 4;
            const bf16x8 aw = *(const bf16x8*)(L + abyt);
            bf16x8 bv[3];
            #pragma unroll
            for (int nt = 0; nt < 3; ++nt) {
                const int h = 16 * nt + lo;
                int byt;
                if (h < HL) {
                    byt = VT_B + h * 256 + (ks * 32 + hi * 8) * 2;
                    byt ^= (h & 7) << 4;
                } else {
                    byt = ZEROP_B;                 // 16 B of masked-zero wei row 0
                }
                bv[nt] = *(const bf16x8*)(L + byt);
            }
            #pragma unroll
            for (int nt = 0; nt < 3; ++nt)
                pa[nt] = __builtin_amdgcn_mfma_f32_16x16x32_bf16(aw, bv[nt], pa[nt], 0, 0, 0);
        }
    }

    // fetch 1/sum for this lane's output rows t = 16*wv + hi*4 + r (held by lane hi*4+r)
    float rsv[4];
    #pragma unroll
    for (int r = 0; r < 4; ++r) rsv[r] = __shfl(rs, hi * 4 + r);

    float* ob = out + (size_t)b * (TL * HL);
    #pragma unroll
    for (int nt = 0; nt < 3; ++nt) {
        #pragma unroll
        for (int r = 0; r < 4; ++r) {
            const int t = 16 * wv + hi * 4 + r;
            const int h = 16 * nt + lo;
            if (t < TL && h < HL) ob[t * HL + h] = pa[nt][r] * rsv[r];
        }
    }
}

extern "C" void kernel_launch(void* const* d_in, const int* in_sizes, int n_in,
                              void* d_out, int out_size, void* d_ws, size_t ws_size,
                              hipStream_t stream) {
    const float* x  = (const float*)d_in[0];
    const float* Wk = (const float*)d_in[1];
    const float* Wq = (const float*)d_in[2];
    const float* Wv = (const float*)d_in[3];
    float* out = (float*)d_out;
    const int B = in_sizes[0] / (TL * CL);   // 4096

    if (ws_size >= (size_t)WS_ELEMS * sizeof(u16)) {
        prepack_w<<<(WS_ELEMS + 255) / 256, 256, 0, stream>>>(Wk, Wq, Wv, (u16*)d_ws);
        head_mfma<1><<<dim3(B), dim3(512), LDS_BYTES, stream>>>(x, Wk, Wq, Wv, (const u16*)d_ws, out);
    } else {
        head_mfma<0><<<dim3(B), dim3(512), LDS_BYTES, stream>>>(x, Wk, Wq, Wv, nullptr, out);
    }
}

// Round 11
// 117.793 us; speedup vs baseline: 2.5074x; 1.1585x over previous
//
#include <hip/hip_runtime.h>

#define TL 124
#define CL 144
#define HL 36

typedef unsigned short u16;
typedef short bf16x8 __attribute__((ext_vector_type(8)));
typedef float f32x4  __attribute__((ext_vector_type(4)));

// LDS (bytes), 62464 total; 512-thread blocks, 2 blocks/CU (124.9 KiB):
//   k   @ 0     : bf16 [128][40] = 10240  (cols 36..39 zeroed; rows >=124 finite garbage)
//   gap @ 10240 : 16 B zeros (phase-S K-tail fragment for hi>=1)
//   q   @ 10256 : bf16 [128][40] = 10240  (ends 20496)
//   W   @ 20496 : bf16 image [18 hk][112 hp][8 j] = 32256 (phase K only; staged in-kernel; dead after)
//   wei @ 0     : bf16 [124][128] = 31744 (overlays k/gap/q + W head after S-barrier; XOR-swizzled; UNNORMALIZED)
//   vT  @ 53248 : bf16 [36][128] = 9216   (vT[h][t], XOR-swizzled) -> ends 62464
// NOTE: VT_B MUST be 256-aligned: the XOR swizzle flips addr bits 4..6, and writes to
// cols 120..127 must not carry into the row bits (r9/r10 bug: VT_B=52752 had bit 4 set,
// aliasing garbage cols 124..127 onto real v data of the next row).
#define KQ_ST   40
#define GAP_B   10240
#define Q_B     10256
#define W_B     20496
#define VT_B    53248
#define ZEROP_B 128     // wei row 0, cols 64..71: masked-zero
#define LDS_BYTES 62464

// k is pre-scaled by log2(e)/12 so scores are in log2 domain: softmax uses raw v_exp_f32 (2^x).
#define SCL_K 0.12022458674074693f

__device__ __forceinline__ u16 f2b(float f) {
    union { float f; unsigned u; } c; c.f = f;
    unsigned u = c.u;
    u += 0x7FFFu + ((u >> 16) & 1u);     // round-to-nearest-even
    return (u16)(u >> 16);
}

__device__ __forceinline__ unsigned cvtpk(float a, float b) {   // [bf16(a) lo | bf16(b) hi]
    unsigned r;
    asm("v_cvt_pk_bf16_f32 %0, %1, %2" : "=v"(r) : "v"(a), "v"(b));
    return r;
}

__device__ __forceinline__ float vexp2(float x) {               // 2^x
    float r;
    asm("v_exp_f32 %0, %1" : "=v"(r) : "v"(x));
    return r;
}

__global__ __launch_bounds__(512, 4)
void head_mfma(const float* __restrict__ x,
               const float* __restrict__ Wk, const float* __restrict__ Wq,
               const float* __restrict__ Wv,
               float* __restrict__ out)
{
    extern __shared__ char lds[];
    char* L = lds;

    const int tid = threadIdx.x;
    const int wv  = tid >> 6;          // wave 0..7 = M-tile
    const int l   = tid & 63;
    const int lo  = l & 15;
    const int hi  = l >> 4;
    const int b   = blockIdx.x;
    const float* xb = x + (size_t)b * (TL * CL);

    // ---- prologue: zero gap + k/q cols 36..39 (all 128 rows) + W image hp 108..111 ----
    if (tid < 2) *(uint2*)(L + GAP_B + tid * 8) = make_uint2(0u, 0u);
    for (int i = tid; i < 256; i += 512) {
        const int buf = i & 1, t = i >> 1;
        *(uint2*)(L + (buf ? Q_B : 0) + t * 80 + 72) = make_uint2(0u, 0u);
    }
    for (int i = tid; i < 72; i += 512) {          // 18 hk x 4 hp x 16 B
        const int hk = i >> 2, r = i & 3;
        *(uint4*)(L + W_B + ((hk * 112 + 108 + r) << 4)) = make_uint4(0u, 0u, 0u, 0u);
    }

    // ---- stage W into LDS image (coalesced f32 reads, u16 scatter writes) ----
    // image semantics (transliterated from the verified global-read formula):
    //   fragment (hk, hp) elem j = W_sec[kc = hk*8 + j][h],  hp = sec*36 + h
    {
        const float* Ws[3] = {Wk, Wq, Wv};
        #pragma unroll
        for (int sec = 0; sec < 3; ++sec) {
            const float* W = Ws[sec];
            for (int i = tid; i < 1296; i += 512) {        // 144 rows x 9 float4
                const int kc = i / 9, c4 = i % 9;
                const float4 v = *(const float4*)(W + kc * HL + c4 * 4);
                const int hk = kc >> 3, j = kc & 7;
                u16* base = (u16*)(L + W_B) + ((hk * 112 + sec * 36 + c4 * 4) << 3) + j;
                base[0]  = f2b(v.x);
                base[8]  = f2b(v.y);
                base[16] = f2b(v.z);
                base[24] = f2b(v.w);
            }
        }
    }
    __syncthreads();   // W image + zeros visible to all waves

    // ---------------- phase K: [k|q|v] = x @ [Wk|Wq|Wv] (MFMA, W from LDS) ----------------
    {
        int trow = 16 * wv + lo;
        if (trow > TL - 1) trow = TL - 1;          // clamp; clamped rows' outputs are discarded
        const float* px = xb + trow * CL;

        f32x4 acc[7];
        #pragma unroll
        for (int n = 0; n < 7; ++n) acc[n] = (f32x4){0.f, 0.f, 0.f, 0.f};

        // x pipeline: current chunk in (cu,cv), next prefetched into (nu,nv).
        // Tail chunk (ks=4, hi>=2) reads past the row into the next row — in-bounds
        // globally (trow<=123) — and is masked to zero.
        float4 cu = *(const float4*)(px + hi * 8);
        float4 cv = *(const float4*)(px + hi * 8 + 4);

        #pragma unroll
        for (int ks = 0; ks < 5; ++ks) {
            float4 nu, nv;
            if (ks < 4) {
                const float* nx = px + (ks + 1) * 32 + hi * 8;
                nu = *(const float4*)(nx);
                nv = *(const float4*)(nx + 4);
            }
            union { unsigned w[4]; bf16x8 h8; } cc;
            cc.w[0] = cvtpk(cu.x, cu.y);
            cc.w[1] = cvtpk(cu.z, cu.w);
            cc.w[2] = cvtpk(cv.x, cv.y);
            cc.w[3] = cvtpk(cv.z, cv.w);
            if (ks == 4 && hi >= 2) { cc.w[0] = 0; cc.w[1] = 0; cc.w[2] = 0; cc.w[3] = 0; }
            const bf16x8 ah = cc.h8;

            // ks=4 exists only for hi<2 (kc 128..143); hi>=2 aliases hk=16 (A is zero there)
            const int hkv = (ks == 4 && hi >= 2) ? 16 : ks * 4 + hi;

            bf16x8 bfr[7];
            #pragma unroll
            for (int nt = 0; nt < 7; ++nt)
                bfr[nt] = *(const bf16x8*)(L + W_B + ((hkv * 112 + 16 * nt + lo) << 4));
            #pragma unroll
            for (int nt = 0; nt < 7; ++nt)
                acc[nt] = __builtin_amdgcn_mfma_f32_16x16x32_bf16(ah, bfr[nt], acc[nt], 0, 0, 0);
            cu = nu; cv = nv;
        }

        // D-writes (unconditional; k/q rows padded to 128): k gets SCL_K folded in.
        const int tb = 16 * wv + hi * 4;
        #pragma unroll
        for (int nt = 0; nt < 7; ++nt) {
            const int hp = 16 * nt + lo;
            float s0 = acc[nt][0], s1 = acc[nt][1], s2 = acc[nt][2], s3 = acc[nt][3];
            if (nt < 3) {                          // only nt 0..2 contain k lanes (hp<36)
                const float m = (hp < 36) ? SCL_K : 1.0f;
                s0 *= m; s1 *= m; s2 *= m; s3 *= m;
            }
            const unsigned w01 = cvtpk(s0, s1);
            const unsigned w23 = cvtpk(s2, s3);
            if (hp < 72) {
                u16* dst = (u16*)(L + ((hp < 36) ? 0 : Q_B));
                const int h = (hp < 36) ? hp : hp - 36;
                dst[(tb + 0) * KQ_ST + h] = (u16)(w01 & 0xffffu);
                dst[(tb + 1) * KQ_ST + h] = (u16)(w01 >> 16);
                dst[(tb + 2) * KQ_ST + h] = (u16)(w23 & 0xffffu);
                dst[(tb + 3) * KQ_ST + h] = (u16)(w23 >> 16);
            } else if (hp < 108) {
                const int hv = hp - 72;
                int byt = VT_B + hv * 256 + tb * 2;
                byt ^= (hv & 7) << 4;
                *(uint2*)(L + byt) = make_uint2(w01, w23);   // t-cols >=124: finite garbage, wei=0 there
            }
        }
    }
    __syncthreads();

    // ---------------- phase S (transposed): D[s][t] = q[s] . k~[t] (k~ pre-scaled) ----------------
    f32x4 sa[8];
    #pragma unroll
    for (int n = 0; n < 8; ++n) sa[n] = (f32x4){0.f, 0.f, 0.f, 0.f};

    {
        const int krow = 16 * wv + lo;             // rows >=124: finite garbage -> t-cols discarded
        const bf16x8 bk0 = *(const bf16x8*)(L + krow * 80 + hi * 16);
        const bf16x8 bk1 = *(const bf16x8*)(L + ((hi == 0) ? (krow * 80 + 64) : GAP_B));
        bf16x8 aq[8];
        #pragma unroll
        for (int nt = 0; nt < 8; ++nt)             // batch 8 loads
            aq[nt] = *(const bf16x8*)(L + Q_B + (16 * nt + lo) * 80 + hi * 16);
        #pragma unroll
        for (int nt = 0; nt < 8; ++nt)
            sa[nt] = __builtin_amdgcn_mfma_f32_16x16x32_bf16(aq[nt], bk0, sa[nt], 0, 0, 0);
        #pragma unroll
        for (int nt = 0; nt < 8; ++nt)
            aq[nt] = *(const bf16x8*)(L + ((hi == 0) ? (Q_B + (16 * nt + lo) * 80 + 64) : GAP_B));
        #pragma unroll
        for (int nt = 0; nt < 8; ++nt)
            sa[nt] = __builtin_amdgcn_mfma_f32_16x16x32_bf16(aq[nt], bk1, sa[nt], 0, 0, 0);
    }
    __syncthreads();   // all k/q reads done before wei overlays them

    // ---------------- softmax (log2 domain): lane owns col t; rows s = 16*nt+4*hi+r ----------------
    float rs;
    {
        const int t = 16 * wv + lo;
        float p[8][4];
        float mx = -__builtin_inff();
        #pragma unroll
        for (int nt = 0; nt < 8; ++nt)
            #pragma unroll
            for (int r = 0; r < 4; ++r) {
                const int s = 16 * nt + 4 * hi + r;
                p[nt][r] = (s <= t) ? sa[nt][r] : -__builtin_inff();
                mx = fmaxf(mx, p[nt][r]);
            }
        mx = fmaxf(mx, __shfl_xor(mx, 16));        // 4 lanes share col t
        mx = fmaxf(mx, __shfl_xor(mx, 32));
        float sum = 0.f;
        #pragma unroll
        for (int nt = 0; nt < 8; ++nt)
            #pragma unroll
            for (int r = 0; r < 4; ++r) {
                const float ex = vexp2(p[nt][r] - mx);   // -inf -> 0
                p[nt][r] = ex;
                sum += ex;
            }
        sum += __shfl_xor(sum, 16);
        sum += __shfl_xor(sum, 32);
        rs = __builtin_amdgcn_rcpf(sum);           // sum >= 1 (max element contributes 1)
        if (t < TL) {                              // t>=124 lanes would overwrite beyond wei rows
            #pragma unroll
            for (int nt = 0; nt < 8; ++nt) {
                const unsigned w01 = cvtpk(p[nt][0], p[nt][1]);   // UNNORMALIZED wei
                const unsigned w23 = cvtpk(p[nt][2], p[nt][3]);
                int byt = t * 256 + (16 * nt + 4 * hi) * 2;
                byt ^= (t & 7) << 4;
                *(uint2*)(L + byt) = make_uint2(w01, w23);
            }
        }
    }
    __syncthreads();

    // ---------------- phase P: out = wei @ v (MFMA), normalize by 1/sum at f32 epilogue ----------------
    f32x4 pa[3];
    #pragma unroll
    for (int n = 0; n < 3; ++n) pa[n] = (f32x4){0.f, 0.f, 0.f, 0.f};

    {
        int wrow = 16 * wv + lo;
        if (wrow > TL - 1) wrow = TL - 1;          // clamp: rows 124..127 discarded
        #pragma unroll
        for (int ks = 0; ks < 4; ++ks) {
            int abyt = wrow * 256 + (ks * 32 + hi * 8) * 2;
            abyt ^= (wrow & 7) << 4;
            const bf16x8 aw = *(const bf16x8*)(L + abyt);
            bf16x8 bv[3];
            #pragma unroll
            for (int nt = 0; nt < 3; ++nt) {
                const int h = 16 * nt + lo;
                int byt;
                if (h < HL) {
                    byt = VT_B + h * 256 + (ks * 32 + hi * 8) * 2;
                    byt ^= (h & 7) << 4;
                } else {
                    byt = ZEROP_B;                 // 16 B of masked-zero wei row 0
                }
                bv[nt] = *(const bf16x8*)(L + byt);
            }
            #pragma unroll
            for (int nt = 0; nt < 3; ++nt)
                pa[nt] = __builtin_amdgcn_mfma_f32_16x16x32_bf16(aw, bv[nt], pa[nt], 0, 0, 0);
        }
    }

    // fetch 1/sum for this lane's output rows t = 16*wv + hi*4 + r (held by lane hi*4+r)
    float rsv[4];
    #pragma unroll
    for (int r = 0; r < 4; ++r) rsv[r] = __shfl(rs, hi * 4 + r);

    float* ob = out + (size_t)b * (TL * HL);
    #pragma unroll
    for (int nt = 0; nt < 3; ++nt) {
        #pragma unroll
        for (int r = 0; r < 4; ++r) {
            const int t = 16 * wv + hi * 4 + r;
            const int h = 16 * nt + lo;
            if (t < TL && h < HL) ob[t * HL + h] = pa[nt][r] * rsv[r];
        }
    }
}

extern "C" void kernel_launch(void* const* d_in, const int* in_sizes, int n_in,
                              void* d_out, int out_size, void* d_ws, size_t ws_size,
                              hipStream_t stream) {
    const float* x  = (const float*)d_in[0];
    const float* Wk = (const float*)d_in[1];
    const float* Wq = (const float*)d_in[2];
    const float* Wv = (const float*)d_in[3];
    float* out = (float*)d_out;
    const int B = in_sizes[0] / (TL * CL);   // 4096
    head_mfma<<<dim3(B), dim3(512), LDS_BYTES, stream>>>(x, Wk, Wq, Wv, out);
}

// Round 12
// 110.043 us; speedup vs baseline: 2.6840x; 1.0704x over previous
//
#include <hip/hip_runtime.h>

#define TL 124
#define CL 144
#define HL 36

typedef unsigned short u16;
typedef short bf16x8 __attribute__((ext_vector_type(8)));
typedef float f32x4  __attribute__((ext_vector_type(4)));

// LDS (bytes), 62464 total; 512-thread blocks, 2 blocks/CU (124.9 KiB):
//   k   @ 0     : bf16 [128][40] = 10240  (cols 36..39 zeroed; rows >=124 finite garbage)
//   gap @ 10240 : 16 B zeros (phase-S K-tail fragment for hi>=1)
//   q   @ 10256 : bf16 [128][40] = 10240  (ends 20496)
//   W   @ 20496 : bf16 image [18 hk][112 hp][8 j] = 32256 (phase K only; staged in-kernel; dead after)
//   wei @ 0     : bf16 [124][128] = 31744 (overlays k/gap/q + W head after S-barrier; XOR-swizzled; UNNORMALIZED)
//   vT  @ 53248 : bf16 [36][128] = 9216   (vT[h][t], XOR-swizzled) -> ends 62464
// NOTE: VT_B MUST be 256-aligned: the XOR swizzle flips addr bits 4..6, and writes to
// cols 120..127 must not carry into the row bits (r9/r10 bug: VT_B=52752 had bit 4 set).
#define KQ_ST   40
#define GAP_B   10240
#define Q_B     10256
#define W_B     20496
#define VT_B    53248
#define ZEROP_B 128     // wei row 0, cols 64..71: masked-zero
#define LDS_BYTES 62464

// k is pre-scaled by log2(e)/12 so scores are in log2 domain: softmax uses raw v_exp_f32 (2^x).
#define SCL_K 0.12022458674074693f

__device__ __forceinline__ unsigned cvtpk(float a, float b) {   // [bf16(a) lo | bf16(b) hi]
    unsigned r;
    asm("v_cvt_pk_bf16_f32 %0, %1, %2" : "=v"(r) : "v"(a), "v"(b));
    return r;
}

__device__ __forceinline__ float vexp2(float x) {               // 2^x
    float r;
    asm("v_exp_f32 %0, %1" : "=v"(r) : "v"(x));
    return r;
}

__global__ __launch_bounds__(512, 4)
void head_mfma(const float* __restrict__ x,
               const float* __restrict__ Wk, const float* __restrict__ Wq,
               const float* __restrict__ Wv,
               float* __restrict__ out)
{
    extern __shared__ char lds[];
    char* L = lds;

    const int tid = threadIdx.x;
    const int wv  = tid >> 6;          // wave 0..7 = M-tile
    const int l   = tid & 63;
    const int lo  = l & 15;
    const int hi  = l >> 4;
    const int b   = blockIdx.x;
    const float* xb = x + (size_t)b * (TL * CL);

    // ---- prologue: zero gap + k/q cols 36..39 (all 128 rows) + W image hp 108..111 ----
    if (tid < 2) *(uint2*)(L + GAP_B + tid * 8) = make_uint2(0u, 0u);
    for (int i = tid; i < 256; i += 512) {
        const int buf = i & 1, t = i >> 1;
        *(uint2*)(L + (buf ? Q_B : 0) + t * 80 + 72) = make_uint2(0u, 0u);
    }
    for (int i = tid; i < 72; i += 512) {          // 18 hk x 4 hp x 16 B
        const int hk = i >> 2, r = i & 3;
        *(uint4*)(L + W_B + ((hk * 112 + 108 + r) << 4)) = make_uint4(0u, 0u, 0u, 0u);
    }

    // ---- stage W into LDS image: 4 coalesced f32 along kc -> 2 cvtpk -> 1 ds_write_b64 ----
    // image elem ((hk*112 + hp)*8 + j) = W_sec[kc = hk*8 + j][h],  hp = sec*36 + h
    for (int i = tid; i < 3888; i += 512) {        // 18 hk x 2 j4 x 108 hp
        const int hk  = i / 216;
        const int rem = i - hk * 216;
        const int j4  = rem / 108;                 // 0..1 (j-half)
        const int hp  = rem - j4 * 108;            // 0..107
        const int sec = hp / 36;
        const int h   = hp - sec * 36;
        const float* W = (sec == 0) ? Wk : (sec == 1) ? Wq : Wv;
        const int kc = hk * 8 + j4 * 4;            // 0..140, kc+3 <= 143
        const float a0 = W[(kc + 0) * HL + h];
        const float a1 = W[(kc + 1) * HL + h];
        const float a2 = W[(kc + 2) * HL + h];
        const float a3 = W[(kc + 3) * HL + h];
        *(uint2*)(L + W_B + ((hk * 112 + hp) << 4) + j4 * 8) =
            make_uint2(cvtpk(a0, a1), cvtpk(a2, a3));
    }
    __syncthreads();   // W image + zeros visible to all waves

    // ---------------- phase K: [k|q|v] = x @ [Wk|Wq|Wv] (MFMA, W from LDS) ----------------
    {
        int trow = 16 * wv + lo;
        if (trow > TL - 1) trow = TL - 1;          // clamp; clamped rows' outputs are discarded
        const float* px = xb + trow * CL;

        f32x4 acc[7];
        #pragma unroll
        for (int n = 0; n < 7; ++n) acc[n] = (f32x4){0.f, 0.f, 0.f, 0.f};

        // x pipeline: current chunk in (cu,cv), next prefetched into (nu,nv).
        // Tail chunk (ks=4, hi>=2) reads past the row into the next row — in-bounds
        // globally (trow<=123) — and is masked to zero.
        float4 cu = *(const float4*)(px + hi * 8);
        float4 cv = *(const float4*)(px + hi * 8 + 4);

        #pragma unroll
        for (int ks = 0; ks < 5; ++ks) {
            float4 nu, nv;
            if (ks < 4) {
                const float* nx = px + (ks + 1) * 32 + hi * 8;
                nu = *(const float4*)(nx);
                nv = *(const float4*)(nx + 4);
            }
            union { unsigned w[4]; bf16x8 h8; } cc;
            cc.w[0] = cvtpk(cu.x, cu.y);
            cc.w[1] = cvtpk(cu.z, cu.w);
            cc.w[2] = cvtpk(cv.x, cv.y);
            cc.w[3] = cvtpk(cv.z, cv.w);
            if (ks == 4 && hi >= 2) { cc.w[0] = 0; cc.w[1] = 0; cc.w[2] = 0; cc.w[3] = 0; }
            const bf16x8 ah = cc.h8;

            // ks=4 exists only for hi<2 (kc 128..143); hi>=2 aliases hk=16 (A is zero there)
            const int hkv = (ks == 4 && hi >= 2) ? 16 : ks * 4 + hi;

            bf16x8 bfr[7];
            #pragma unroll
            for (int nt = 0; nt < 7; ++nt)
                bfr[nt] = *(const bf16x8*)(L + W_B + ((hkv * 112 + 16 * nt + lo) << 4));
            __builtin_amdgcn_s_setprio(1);
            #pragma unroll
            for (int nt = 0; nt < 7; ++nt)
                acc[nt] = __builtin_amdgcn_mfma_f32_16x16x32_bf16(ah, bfr[nt], acc[nt], 0, 0, 0);
            __builtin_amdgcn_s_setprio(0);
            cu = nu; cv = nv;
        }

        // D-writes (unconditional; k/q rows padded to 128): k gets SCL_K folded in.
        const int tb = 16 * wv + hi * 4;
        #pragma unroll
        for (int nt = 0; nt < 7; ++nt) {
            const int hp = 16 * nt + lo;
            float s0 = acc[nt][0], s1 = acc[nt][1], s2 = acc[nt][2], s3 = acc[nt][3];
            if (nt < 3) {                          // only nt 0..2 contain k lanes (hp<36)
                const float m = (hp < 36) ? SCL_K : 1.0f;
                s0 *= m; s1 *= m; s2 *= m; s3 *= m;
            }
            const unsigned w01 = cvtpk(s0, s1);
            const unsigned w23 = cvtpk(s2, s3);
            if (hp < 72) {
                u16* dst = (u16*)(L + ((hp < 36) ? 0 : Q_B));
                const int h = (hp < 36) ? hp : hp - 36;
                dst[(tb + 0) * KQ_ST + h] = (u16)(w01 & 0xffffu);
                dst[(tb + 1) * KQ_ST + h] = (u16)(w01 >> 16);
                dst[(tb + 2) * KQ_ST + h] = (u16)(w23 & 0xffffu);
                dst[(tb + 3) * KQ_ST + h] = (u16)(w23 >> 16);
            } else if (hp < 108) {
                const int hv = hp - 72;
                int byt = VT_B + hv * 256 + tb * 2;
                byt ^= (hv & 7) << 4;
                *(uint2*)(L + byt) = make_uint2(w01, w23);   // t-cols >=124: finite garbage, wei=0 there
            }
        }
    }
    __syncthreads();

    // ---------------- phase S (transposed): D[s][t] = q[s] . k~[t] (k~ pre-scaled) ----------------
    f32x4 sa[8];
    #pragma unroll
    for (int n = 0; n < 8; ++n) sa[n] = (f32x4){0.f, 0.f, 0.f, 0.f};

    {
        const int krow = 16 * wv + lo;             // rows >=124: finite garbage -> t-cols discarded
        const bf16x8 bk0 = *(const bf16x8*)(L + krow * 80 + hi * 16);
        const bf16x8 bk1 = *(const bf16x8*)(L + ((hi == 0) ? (krow * 80 + 64) : GAP_B));
        bf16x8 aq[8];
        #pragma unroll
        for (int nt = 0; nt < 8; ++nt)             // batch 8 loads
            aq[nt] = *(const bf16x8*)(L + Q_B + (16 * nt + lo) * 80 + hi * 16);
        __builtin_amdgcn_s_setprio(1);
        #pragma unroll
        for (int nt = 0; nt < 8; ++nt)
            sa[nt] = __builtin_amdgcn_mfma_f32_16x16x32_bf16(aq[nt], bk0, sa[nt], 0, 0, 0);
        __builtin_amdgcn_s_setprio(0);
        #pragma unroll
        for (int nt = 0; nt < 8; ++nt)
            aq[nt] = *(const bf16x8*)(L + ((hi == 0) ? (Q_B + (16 * nt + lo) * 80 + 64) : GAP_B));
        __builtin_amdgcn_s_setprio(1);
        #pragma unroll
        for (int nt = 0; nt < 8; ++nt)
            sa[nt] = __builtin_amdgcn_mfma_f32_16x16x32_bf16(aq[nt], bk1, sa[nt], 0, 0, 0);
        __builtin_amdgcn_s_setprio(0);
    }
    __syncthreads();   // all k/q reads done before wei overlays them

    // ---------------- softmax (log2 domain): lane owns col t; rows s = 16*nt+4*hi+r ----------------
    float rs;
    {
        const int t = 16 * wv + lo;
        float p[8][4];
        float mx = -__builtin_inff();
        #pragma unroll
        for (int nt = 0; nt < 8; ++nt)
            #pragma unroll
            for (int r = 0; r < 4; ++r) {
                const int s = 16 * nt + 4 * hi + r;
                p[nt][r] = (s <= t) ? sa[nt][r] : -__builtin_inff();
                mx = fmaxf(mx, p[nt][r]);
            }
        mx = fmaxf(mx, __shfl_xor(mx, 16));        // 4 lanes share col t
        mx = fmaxf(mx, __shfl_xor(mx, 32));
        float sum = 0.f;
        #pragma unroll
        for (int nt = 0; nt < 8; ++nt)
            #pragma unroll
            for (int r = 0; r < 4; ++r) {
                const float ex = vexp2(p[nt][r] - mx);   // -inf -> 0
                p[nt][r] = ex;
                sum += ex;
            }
        sum += __shfl_xor(sum, 16);
        sum += __shfl_xor(sum, 32);
        rs = __builtin_amdgcn_rcpf(sum);           // sum >= 1 (max element contributes 1)
        if (t < TL) {                              // t>=124 lanes would overwrite beyond wei rows
            #pragma unroll
            for (int nt = 0; nt < 8; ++nt) {
                const unsigned w01 = cvtpk(p[nt][0], p[nt][1]);   // UNNORMALIZED wei
                const unsigned w23 = cvtpk(p[nt][2], p[nt][3]);
                int byt = t * 256 + (16 * nt + 4 * hi) * 2;
                byt ^= (t & 7) << 4;
                *(uint2*)(L + byt) = make_uint2(w01, w23);
            }
        }
    }
    __syncthreads();

    // ---------------- phase P: out = wei @ v (MFMA), normalize by 1/sum at f32 epilogue ----------------
    f32x4 pa[3];
    #pragma unroll
    for (int n = 0; n < 3; ++n) pa[n] = (f32x4){0.f, 0.f, 0.f, 0.f};

    {
        int wrow = 16 * wv + lo;
        if (wrow > TL - 1) wrow = TL - 1;          // clamp: rows 124..127 discarded
        #pragma unroll
        for (int ks = 0; ks < 4; ++ks) {
            int abyt = wrow * 256 + (ks * 32 + hi * 8) * 2;
            abyt ^= (wrow & 7) << 4;
            const bf16x8 aw = *(const bf16x8*)(L + abyt);
            bf16x8 bv[3];
            #pragma unroll
            for (int nt = 0; nt < 3; ++nt) {
                const int h = 16 * nt + lo;
                int byt;
                if (h < HL) {
                    byt = VT_B + h * 256 + (ks * 32 + hi * 8) * 2;
                    byt ^= (h & 7) << 4;
                } else {
                    byt = ZEROP_B;                 // 16 B of masked-zero wei row 0
                }
                bv[nt] = *(const bf16x8*)(L + byt);
            }
            __builtin_amdgcn_s_setprio(1);
            #pragma unroll
            for (int nt = 0; nt < 3; ++nt)
                pa[nt] = __builtin_amdgcn_mfma_f32_16x16x32_bf16(aw, bv[nt], pa[nt], 0, 0, 0);
            __builtin_amdgcn_s_setprio(0);
        }
    }

    // fetch 1/sum for this lane's output rows t = 16*wv + hi*4 + r (held by lane hi*4+r)
    float rsv[4];
    #pragma unroll
    for (int r = 0; r < 4; ++r) rsv[r] = __shfl(rs, hi * 4 + r);

    float* ob = out + (size_t)b * (TL * HL);
    #pragma unroll
    for (int nt = 0; nt < 3; ++nt) {
        #pragma unroll
        for (int r = 0; r < 4; ++r) {
            const int t = 16 * wv + hi * 4 + r;
            const int h = 16 * nt + lo;
            if (t < TL && h < HL) ob[t * HL + h] = pa[nt][r] * rsv[r];
        }
    }
}

extern "C" void kernel_launch(void* const* d_in, const int* in_sizes, int n_in,
                              void* d_out, int out_size, void* d_ws, size_t ws_size,
                              hipStream_t stream) {
    const float* x  = (const float*)d_in[0];
    const float* Wk = (const float*)d_in[1];
    const float* Wq = (const float*)d_in[2];
    const float* Wv = (const float*)d_in[3];
    float* out = (float*)d_out;
    const int B = in_sizes[0] / (TL * CL);   // 4096
    head_mfma<<<dim3(B), dim3(512), LDS_BYTES, stream>>>(x, Wk, Wq, Wv, out);
}

// Round 13
// 104.136 us; speedup vs baseline: 2.8363x; 1.0567x over previous
//
#include <hip/hip_runtime.h>

#define TL 124
#define CL 144
#define HL 36

typedef unsigned short u16;
typedef short bf16x8 __attribute__((ext_vector_type(8)));
typedef float f32x4  __attribute__((ext_vector_type(4)));

// LDS (bytes), 52752 total; 512-thread blocks, 3 blocks/CU (158.3 KiB):
//   k   @ 0     : bf16 [128][40] = 10240  (cols 36..39 zeroed; rows >=124 finite garbage)
//   gap @ 10240 : 16 B zeros (phase-S K-tail fragment for hi>=1)
//   q   @ 10256 : bf16 [128][40] = 10240  (ends 20496)
//   W   @ 20496 : bf16 image [18 hk][112 hp][8 j] = 32256 (phase K only; dead after post-K barrier)
//   wei @ 0     : bf16 [124][128] = 31744 (overlays k/gap/q + W head after S-barrier; XOR-swizzled; UNNORMALIZED)
//   vT  @ 31744 : bf16 [36][128] = 9216   (vT[h][t], XOR-swizzled) — lives in the DEAD W region;
//                 v fragments are held in registers through the post-K barrier, then written here.
// NOTE: VT_B MUST be 256-aligned: the XOR swizzle flips addr bits 4..6 (r9/r10 bug).
#define KQ_ST   40
#define GAP_B   10240
#define Q_B     10256
#define W_B     20496
#define VT_B    31744
#define ZEROP_B 128     // wei row 0, cols 64..71: masked-zero
#define LDS_BYTES 52752

// k is pre-scaled by log2(e)/12 so scores are in log2 domain: softmax uses raw v_exp_f32 (2^x).
#define SCL_K 0.12022458674074693f

__device__ __forceinline__ unsigned cvtpk(float a, float b) {   // [bf16(a) lo | bf16(b) hi]
    unsigned r;
    asm("v_cvt_pk_bf16_f32 %0, %1, %2" : "=v"(r) : "v"(a), "v"(b));
    return r;
}

__device__ __forceinline__ float vexp2(float x) {               // 2^x
    float r;
    asm("v_exp_f32 %0, %1" : "=v"(r) : "v"(x));
    return r;
}

__global__ __launch_bounds__(512, 6)
void head_mfma(const float* __restrict__ x,
               const float* __restrict__ Wk, const float* __restrict__ Wq,
               const float* __restrict__ Wv,
               float* __restrict__ out)
{
    extern __shared__ char lds[];
    char* L = lds;

    const int tid = threadIdx.x;
    const int wv  = tid >> 6;          // wave 0..7 = M-tile
    const int l   = tid & 63;
    const int lo  = l & 15;
    const int hi  = l >> 4;
    const int b   = blockIdx.x;
    const float* xb = x + (size_t)b * (TL * CL);

    // ---- prologue: zero gap + k/q cols 36..39 (all 128 rows) + W image hp 108..111 ----
    if (tid < 2) *(uint2*)(L + GAP_B + tid * 8) = make_uint2(0u, 0u);
    for (int i = tid; i < 256; i += 512) {
        const int buf = i & 1, t = i >> 1;
        *(uint2*)(L + (buf ? Q_B : 0) + t * 80 + 72) = make_uint2(0u, 0u);
    }
    for (int i = tid; i < 72; i += 512) {          // 18 hk x 4 hp x 16 B
        const int hk = i >> 2, r = i & 3;
        *(uint4*)(L + W_B + ((hk * 112 + 108 + r) << 4)) = make_uint4(0u, 0u, 0u, 0u);
    }

    // ---- stage W into LDS image: 4 coalesced f32 along kc -> 2 cvtpk -> 1 ds_write_b64 ----
    // image elem ((hk*112 + hp)*8 + j) = W_sec[kc = hk*8 + j][h],  hp = sec*36 + h
    for (int i = tid; i < 3888; i += 512) {        // 18 hk x 2 j4 x 108 hp
        const int hk  = i / 216;
        const int rem = i - hk * 216;
        const int j4  = rem / 108;                 // 0..1 (j-half)
        const int hp  = rem - j4 * 108;            // 0..107
        const int sec = hp / 36;
        const int h   = hp - sec * 36;
        const float* W = (sec == 0) ? Wk : (sec == 1) ? Wq : Wv;
        const int kc = hk * 8 + j4 * 4;            // 0..140, kc+3 <= 143
        const float a0 = W[(kc + 0) * HL + h];
        const float a1 = W[(kc + 1) * HL + h];
        const float a2 = W[(kc + 2) * HL + h];
        const float a3 = W[(kc + 3) * HL + h];
        *(uint2*)(L + W_B + ((hk * 112 + hp) << 4) + j4 * 8) =
            make_uint2(cvtpk(a0, a1), cvtpk(a2, a3));
    }
    __syncthreads();   // W image + zeros visible to all waves

    // ---------------- phase K: [k|q|v] = x @ [Wk|Wq|Wv] (MFMA, W from LDS) ----------------
    uint2 vstash[3]; int vbyt[3]; bool vok[3];     // deferred vT fragments (written after barrier)
    #pragma unroll
    for (int m = 0; m < 3; ++m) vok[m] = false;
    {
        int trow = 16 * wv + lo;
        if (trow > TL - 1) trow = TL - 1;          // clamp; clamped rows' outputs are discarded
        const float* px = xb + trow * CL;

        f32x4 acc[7];
        #pragma unroll
        for (int n = 0; n < 7; ++n) acc[n] = (f32x4){0.f, 0.f, 0.f, 0.f};

        // x pipeline: current chunk in (cu,cv), next prefetched into (nu,nv).
        // Tail chunk (ks=4, hi>=2) reads past the row into the next row — in-bounds
        // globally (trow<=123) — and is masked to zero.
        float4 cu = *(const float4*)(px + hi * 8);
        float4 cv = *(const float4*)(px + hi * 8 + 4);

        #pragma unroll
        for (int ks = 0; ks < 5; ++ks) {
            float4 nu, nv;
            if (ks < 4) {
                const float* nx = px + (ks + 1) * 32 + hi * 8;
                nu = *(const float4*)(nx);
                nv = *(const float4*)(nx + 4);
            }
            union { unsigned w[4]; bf16x8 h8; } cc;
            cc.w[0] = cvtpk(cu.x, cu.y);
            cc.w[1] = cvtpk(cu.z, cu.w);
            cc.w[2] = cvtpk(cv.x, cv.y);
            cc.w[3] = cvtpk(cv.z, cv.w);
            if (ks == 4 && hi >= 2) { cc.w[0] = 0; cc.w[1] = 0; cc.w[2] = 0; cc.w[3] = 0; }
            const bf16x8 ah = cc.h8;

            // ks=4 exists only for hi<2 (kc 128..143); hi>=2 aliases hk=16 (A is zero there)
            const int hkv = (ks == 4 && hi >= 2) ? 16 : ks * 4 + hi;

            bf16x8 bfr[7];
            #pragma unroll
            for (int nt = 0; nt < 7; ++nt)
                bfr[nt] = *(const bf16x8*)(L + W_B + ((hkv * 112 + 16 * nt + lo) << 4));
            __builtin_amdgcn_s_setprio(1);
            #pragma unroll
            for (int nt = 0; nt < 7; ++nt)
                acc[nt] = __builtin_amdgcn_mfma_f32_16x16x32_bf16(ah, bfr[nt], acc[nt], 0, 0, 0);
            __builtin_amdgcn_s_setprio(0);
            cu = nu; cv = nv;
        }

        // D-writes: k/q written now (their buffers are disjoint from W);
        // v fragments STASHED in regs — W region is still live until the barrier.
        const int tb = 16 * wv + hi * 4;
        #pragma unroll
        for (int nt = 0; nt < 7; ++nt) {
            const int hp = 16 * nt + lo;
            float s0 = acc[nt][0], s1 = acc[nt][1], s2 = acc[nt][2], s3 = acc[nt][3];
            if (nt < 3) {                          // only nt 0..2 contain k lanes (hp<36)
                const float m = (hp < 36) ? SCL_K : 1.0f;
                s0 *= m; s1 *= m; s2 *= m; s3 *= m;
            }
            const unsigned w01 = cvtpk(s0, s1);
            const unsigned w23 = cvtpk(s2, s3);
            if (hp < 72) {
                u16* dst = (u16*)(L + ((hp < 36) ? 0 : Q_B));
                const int h = (hp < 36) ? hp : hp - 36;
                dst[(tb + 0) * KQ_ST + h] = (u16)(w01 & 0xffffu);
                dst[(tb + 1) * KQ_ST + h] = (u16)(w01 >> 16);
                dst[(tb + 2) * KQ_ST + h] = (u16)(w23 & 0xffffu);
                dst[(tb + 3) * KQ_ST + h] = (u16)(w23 >> 16);
            } else if (nt >= 4 && hp < 108) {      // v lanes (hp>=72 implies nt>=4)
                const int hv = hp - 72;
                int byt = VT_B + hv * 256 + tb * 2;
                byt ^= (hv & 7) << 4;
                vstash[nt - 4] = make_uint2(w01, w23);
                vbyt[nt - 4] = byt;
                vok[nt - 4] = true;
            }
        }
    }
    __syncthreads();   // all W reads + k/q writes complete; W region now dead

    // deferred vT writes into the dead W region (visible to phase P via the next 2 barriers)
    #pragma unroll
    for (int m = 0; m < 3; ++m)
        if (vok[m]) *(uint2*)(L + vbyt[m]) = vstash[m];

    // ---------------- phase S (transposed): D[s][t] = q[s] . k~[t] (k~ pre-scaled) ----------------
    f32x4 sa[8];
    #pragma unroll
    for (int n = 0; n < 8; ++n) sa[n] = (f32x4){0.f, 0.f, 0.f, 0.f};

    {
        const int krow = 16 * wv + lo;             // rows >=124: finite garbage -> t-cols discarded
        const bf16x8 bk0 = *(const bf16x8*)(L + krow * 80 + hi * 16);
        const bf16x8 bk1 = *(const bf16x8*)(L + ((hi == 0) ? (krow * 80 + 64) : GAP_B));
        bf16x8 aq[8];
        #pragma unroll
        for (int nt = 0; nt < 8; ++nt)             // batch 8 loads
            aq[nt] = *(const bf16x8*)(L + Q_B + (16 * nt + lo) * 80 + hi * 16);
        __builtin_amdgcn_s_setprio(1);
        #pragma unroll
        for (int nt = 0; nt < 8; ++nt)
            sa[nt] = __builtin_amdgcn_mfma_f32_16x16x32_bf16(aq[nt], bk0, sa[nt], 0, 0, 0);
        __builtin_amdgcn_s_setprio(0);
        #pragma unroll
        for (int nt = 0; nt < 8; ++nt)
            aq[nt] = *(const bf16x8*)(L + ((hi == 0) ? (Q_B + (16 * nt + lo) * 80 + 64) : GAP_B));
        __builtin_amdgcn_s_setprio(1);
        #pragma unroll
        for (int nt = 0; nt < 8; ++nt)
            sa[nt] = __builtin_amdgcn_mfma_f32_16x16x32_bf16(aq[nt], bk1, sa[nt], 0, 0, 0);
        __builtin_amdgcn_s_setprio(0);
    }
    __syncthreads();   // all k/q reads done before wei overlays them

    // ---------------- softmax (log2 domain): lane owns col t; rows s = 16*nt+4*hi+r ----------------
    float rs;
    {
        const int t = 16 * wv + lo;
        float p[8][4];
        float mx = -__builtin_inff();
        #pragma unroll
        for (int nt = 0; nt < 8; ++nt)
            #pragma unroll
            for (int r = 0; r < 4; ++r) {
                const int s = 16 * nt + 4 * hi + r;
                p[nt][r] = (s <= t) ? sa[nt][r] : -__builtin_inff();
                mx = fmaxf(mx, p[nt][r]);
            }
        mx = fmaxf(mx, __shfl_xor(mx, 16));        // 4 lanes share col t
        mx = fmaxf(mx, __shfl_xor(mx, 32));
        float sum = 0.f;
        #pragma unroll
        for (int nt = 0; nt < 8; ++nt)
            #pragma unroll
            for (int r = 0; r < 4; ++r) {
                const float ex = vexp2(p[nt][r] - mx);   // -inf -> 0
                p[nt][r] = ex;
                sum += ex;
            }
        sum += __shfl_xor(sum, 16);
        sum += __shfl_xor(sum, 32);
        rs = __builtin_amdgcn_rcpf(sum);           // sum >= 1 (max element contributes 1)
        if (t < TL) {                              // t>=124 lanes would overwrite beyond wei rows
            #pragma unroll
            for (int nt = 0; nt < 8; ++nt) {
                const unsigned w01 = cvtpk(p[nt][0], p[nt][1]);   // UNNORMALIZED wei
                const unsigned w23 = cvtpk(p[nt][2], p[nt][3]);
                int byt = t * 256 + (16 * nt + 4 * hi) * 2;
                byt ^= (t & 7) << 4;
                *(uint2*)(L + byt) = make_uint2(w01, w23);
            }
        }
    }
    __syncthreads();

    // ---------------- phase P: out = wei @ v (MFMA), normalize by 1/sum at f32 epilogue ----------------
    f32x4 pa[3];
    #pragma unroll
    for (int n = 0; n < 3; ++n) pa[n] = (f32x4){0.f, 0.f, 0.f, 0.f};

    {
        int wrow = 16 * wv + lo;
        if (wrow > TL - 1) wrow = TL - 1;          // clamp: rows 124..127 discarded
        #pragma unroll
        for (int ks = 0; ks < 4; ++ks) {
            int abyt = wrow * 256 + (ks * 32 + hi * 8) * 2;
            abyt ^= (wrow & 7) << 4;
            const bf16x8 aw = *(const bf16x8*)(L + abyt);
            bf16x8 bv[3];
            #pragma unroll
            for (int nt = 0; nt < 3; ++nt) {
                const int h = 16 * nt + lo;
                int byt;
                if (h < HL) {
                    byt = VT_B + h * 256 + (ks * 32 + hi * 8) * 2;
                    byt ^= (h & 7) << 4;
                } else {
                    byt = ZEROP_B;                 // 16 B of masked-zero wei row 0
                }
                bv[nt] = *(const bf16x8*)(L + byt);
            }
            __builtin_amdgcn_s_setprio(1);
            #pragma unroll
            for (int nt = 0; nt < 3; ++nt)
                pa[nt] = __builtin_amdgcn_mfma_f32_16x16x32_bf16(aw, bv[nt], pa[nt], 0, 0, 0);
            __builtin_amdgcn_s_setprio(0);
        }
    }

    // fetch 1/sum for this lane's output rows t = 16*wv + hi*4 + r (held by lane hi*4+r)
    float rsv[4];
    #pragma unroll
    for (int r = 0; r < 4; ++r) rsv[r] = __shfl(rs, hi * 4 + r);

    float* ob = out + (size_t)b * (TL * HL);
    #pragma unroll
    for (int nt = 0; nt < 3; ++nt) {
        #pragma unroll
        for (int r = 0; r < 4; ++r) {
            const int t = 16 * wv + hi * 4 + r;
            const int h = 16 * nt + lo;
            if (t < TL && h < HL) ob[t * HL + h] = pa[nt][r] * rsv[r];
        }
    }
}

extern "C" void kernel_launch(void* const* d_in, const int* in_sizes, int n_in,
                              void* d_out, int out_size, void* d_ws, size_t ws_size,
                              hipStream_t stream) {
    const float* x  = (const float*)d_in[0];
    const float* Wk = (const float*)d_in[1];
    const float* Wq = (const float*)d_in[2];
    const float* Wv = (const float*)d_in[3];
    float* out = (float*)d_out;
    const int B = in_sizes[0] / (TL * CL);   // 4096
    head_mfma<<<dim3(B), dim3(512), LDS_BYTES, stream>>>(x, Wk, Wq, Wv, out);
}